// Round 1
// baseline (409.983 us; speedup 1.0000x reference)
//
#include <hip/hip_runtime.h>

#define GN 4096
#define GF 128
#define GB 4

typedef __attribute__((ext_vector_type(8))) short short8;
typedef __attribute__((ext_vector_type(4))) float floatx4;

static __device__ __forceinline__ unsigned short f2bf(float x){
  unsigned int u = __float_as_uint(x);
  u += 0x7FFFu + ((u >> 16) & 1u);            // RNE
  return (unsigned short)(u >> 16);
}

// ---------- Kernel 1: Wh = h@W (f32), si, bf16 E/F tables, bf16 Wh fragment-major ----------
// whB layout: [b][jblk=j>>5][o][j&31] so a wave's B-fragment load is 1KB contiguous.
__global__ __launch_bounds__(256)
void gat_prep(const float* __restrict__ h, const float* __restrict__ W,
              const float* __restrict__ a, unsigned short* __restrict__ whB,
              float* __restrict__ si_g, unsigned short* __restrict__ EFh)
{
  __shared__ float hl[16*GF];                  // 8 KB
  __shared__ float red[2][2][16];
  const int tid = threadIdx.x;
  const int b   = blockIdx.x >> 8;
  const int r0  = (blockIdx.x & 255) << 4;
  const int o = tid & 127, g = tid >> 7;

  const float4* hb4 = (const float4*)(h + ((size_t)(b*GN + r0))*GF);
  ((float4*)hl)[tid]       = hb4[tid];
  ((float4*)hl)[tid + 256] = hb4[tid + 256];
  __syncthreads();

  float acc[8];
  #pragma unroll
  for (int r=0;r<8;++r) acc[r] = 0.f;
  const float* Wp = W + o;
  for (int f4=0; f4<32; ++f4){
    const float w0 = Wp[(f4*4+0)*GF];
    const float w1 = Wp[(f4*4+1)*GF];
    const float w2 = Wp[(f4*4+2)*GF];
    const float w3 = Wp[(f4*4+3)*GF];
    #pragma unroll
    for (int r=0;r<8;++r){
      const float4 h4 = *(const float4*)&hl[((g<<3)+r)*GF + (f4<<2)];
      acc[r] = fmaf(h4.x, w0, acc[r]);
      acc[r] = fmaf(h4.y, w1, acc[r]);
      acc[r] = fmaf(h4.z, w2, acc[r]);
      acc[r] = fmaf(h4.w, w3, acc[r]);
    }
  }

  const float ai = a[o], aj = a[GF + o];
  const int lane = tid & 63, wh = (tid >> 6) & 1;
  #pragma unroll
  for (int r=0;r<8;++r){
    float vi = acc[r]*ai, vj = acc[r]*aj;
    #pragma unroll
    for (int off=32; off; off>>=1){ vi += __shfl_down(vi, off); vj += __shfl_down(vj, off); }
    if (lane == 0){ red[0][wh][(g<<3)+r] = vi; red[1][wh][(g<<3)+r] = vj; }
  }

  // fragment-major bf16 store
  unsigned short us[8] __attribute__((aligned(16)));
  #pragma unroll
  for (int r=0;r<8;++r) us[r] = f2bf(acc[r]);
  {
    const int j0 = r0 + (g<<3);
    unsigned short* dst = whB + (((size_t)(b*128 + (j0>>5))*128 + o)<<5) + (j0&31);
    *(uint4*)dst = *(const uint4*)us;
  }

  __syncthreads();
  if (tid < 16){
    si_g[b*GN + r0 + tid] = red[0][0][tid] + red[0][1][tid];
  } else if (tid < 32){
    const int r = tid - 16;
    const float vsj = red[1][0][r] + red[1][1][r];
    EFh[(size_t)b*8192 + r0 + r]        = f2bf(__expf(vsj));
    EFh[(size_t)b*8192 + 4096 + r0 + r] = f2bf(__expf(0.2f*vsj));
  }
}

// ---------- Kernel 2: fused adj-stream + attention + PV, per-wave pipeline ----------
// Waves are independent over their own 1024-j range: pack bits for chunk c+1 while
// doing MFMA on chunk c; bits double-buffered in private LDS; no mid-kernel barrier.
// Load order per iteration: Bc (L2) first, adj (HBM) after, so vmcnt's oldest-first
// drain never forces the adj prefetch to complete before the MFMA of this chunk.
__global__ __launch_bounds__(256, 2)
void gat_main(const int* __restrict__ adj, const unsigned short* __restrict__ whB,
              const float* __restrict__ si_g, const unsigned short* __restrict__ EFh,
              float* __restrict__ out)
{
  __shared__ __align__(16) char smem[34304];
  unsigned short* sEj = (unsigned short*)smem;                       // [0,4096):E [4096,8192):F (bf16)
  unsigned long long* bits64 = (unsigned long long*)(smem + 16384);  // [4 waves][2 buf][32 rows]
  float* smemc = (float*)smem;                                       // combine (after K-loop)

  const int tid  = threadIdx.x;
  const int wave = tid >> 6, lane = tid & 63;
  const int b  = (blockIdx.x >> 1) & 3;                              // XCD-pair per batch
  const int i0 = ((((blockIdx.x >> 3) << 1) | (blockIdx.x & 1))) << 5;
  const int m = lane & 15, quad = lane >> 4, q8 = quad << 3;
  const int jw = wave << 10, jw32 = wave << 5;

  // --- EF staging (16KB) ---
  {
    const uint4* Eg = (const uint4*)(EFh + (size_t)b*8192);
    uint4* sE4 = (uint4*)sEj;
    #pragma unroll
    for (int k=0;k<4;++k) sE4[tid + (k<<8)] = Eg[tid + (k<<8)];
  }

  const int* adjb = adj + ((size_t)(b*GN + i0))*GN + jw + lane;

  // prologue: issue chunk-0 adj loads (32 rows x 64 j, this wave's range)
  int vv[32];
  #pragma unroll
  for (int r=0;r<32;++r) vv[r] = __builtin_nontemporal_load(adjb + (size_t)r*GN);

  const float si0 = si_g[(size_t)b*GN + i0 + m];
  const float si1 = si_g[(size_t)b*GN + i0 + 16 + m];
  const float Ri0 = __expf(-0.8f*si0), Ri1 = __expf(-0.8f*si1);
  const unsigned short* lanebase = whB + ((size_t)b<<19) + (m<<5) + q8;

  floatx4 acc0[8], acc1[8];
  #pragma unroll
  for (int c=0;c<8;++c){ acc0[c] = (floatx4){0.f,0.f,0.f,0.f}; acc1[c] = (floatx4){0.f,0.f,0.f,0.f}; }
  floatx4 lf0 = (floatx4){0.f,0.f,0.f,0.f}, lf1 = (floatx4){0.f,0.f,0.f,0.f};
  const short8 ones8 = {0x3F80,0x3F80,0x3F80,0x3F80,0x3F80,0x3F80,0x3F80,0x3F80};

// ballot-pack the 32x64 adj chunk held in vv into bits64 buffer bufw_
#define BALLOTS(bufw_) do { \
    unsigned long long* bw = bits64 + (((wave<<1) | (bufw_)) << 5); \
    _Pragma("unroll") \
    for (int r=0;r<32;++r){ \
      const unsigned long long mm = __ballot(vv[r] > 0); \
      if (lane == 0) bw[r] = mm; \
    } \
  } while(0)

// leaky-relu softmax weight: select(E>Ti, E, Ri*F) == fmax(E, Ri*F)  (same condition sj>-si)
#define MKAF(dst_, sh_, Ri_) do { \
    unsigned int aw[4]; \
    _Pragma("unroll") \
    for (int p=0;p<4;++p){ \
      const unsigned int e0 = Eu[p] << 16, e1 = Eu[p] & 0xFFFF0000u; \
      const unsigned int f0 = Fu[p] << 16, f1 = Fu[p] & 0xFFFF0000u; \
      const float p0 = fmaxf(__uint_as_float(e0), (Ri_)*__uint_as_float(f0)); \
      const float p1 = fmaxf(__uint_as_float(e1), (Ri_)*__uint_as_float(f1)); \
      const unsigned int k0 = (unsigned int)(((int)((sh_) << (31-(2*p))))   >> 31); \
      const unsigned int k1 = (unsigned int)(((int)((sh_) << (31-(2*p+1)))) >> 31); \
      const unsigned int b0 = __float_as_uint(p0) & k0; \
      const unsigned int b1 = __float_as_uint(p1) & k1; \
      aw[p] = ((b0 + 0x8000u) >> 16) | ((b1 + 0x8000u) & 0xFFFF0000u); \
    } \
    dst_ = *(const short8*)aw; \
  } while(0)

// one 32-j MFMA step: read bits (buf=cc&1) + E/F, build A-fragments, 18 MFMA
#define COMPUTE_T(cc_, t_, Bc_) do { \
    const unsigned int* bwp = (const unsigned int*)(bits64 + (((wave<<1) | ((cc_)&1)) << 5)); \
    const unsigned int sh0 = bwp[(m<<1) | (t_)] >> q8; \
    const unsigned int sh1 = bwp[((m+16)<<1) | (t_)] >> q8; \
    const int jj = jw + ((((cc_)<<1)|(t_))<<5) + q8; \
    const short8 Es = *(const short8*)&sEj[jj]; \
    const short8 Fs = *(const short8*)&sEj[4096 + jj]; \
    const unsigned int* Eu = (const unsigned int*)&Es; \
    const unsigned int* Fu = (const unsigned int*)&Fs; \
    short8 af0, af1; \
    MKAF(af0, sh0, Ri0); \
    MKAF(af1, sh1, Ri1); \
    _Pragma("unroll") \
    for (int c=0;c<8;++c){ \
      acc0[c] = __builtin_amdgcn_mfma_f32_16x16x32_bf16(af0, Bc_[c], acc0[c], 0, 0, 0); \
      acc1[c] = __builtin_amdgcn_mfma_f32_16x16x32_bf16(af1, Bc_[c], acc1[c], 0, 0, 0); \
    } \
    lf0 = __builtin_amdgcn_mfma_f32_16x16x32_bf16(af0, ones8, lf0, 0, 0, 0); \
    lf1 = __builtin_amdgcn_mfma_f32_16x16x32_bf16(af1, ones8, lf1, 0, 0, 0); \
  } while(0)

  __syncthreads();                 // sEj staged (chunk-0 adj loads already in flight)

  BALLOTS(0);
  asm volatile("s_waitcnt lgkmcnt(0)" ::: "memory");

  #pragma unroll 1
  for (int cc = 0; cc < 15; ++cc){
    // B-fragments for both 32-j steps of this chunk (L2-resident whB) — issued FIRST
    short8 Bc0[8], Bc1[8];
    const unsigned short* wb0 = lanebase + ((size_t)(jw32 + (cc<<1)) << 12);
    #pragma unroll
    for (int c=0;c<8;++c) Bc0[c] = *(const short8*)(wb0 + (c<<9));
    #pragma unroll
    for (int c=0;c<8;++c) Bc1[c] = *(const short8*)(wb0 + 4096 + (c<<9));
    // next adj chunk (HBM) — stays in flight across both compute steps
    #pragma unroll
    for (int r=0;r<32;++r) vv[r] = __builtin_nontemporal_load(adjb + ((cc+1)<<6) + (size_t)r*GN);

    COMPUTE_T(cc, 0, Bc0);
    COMPUTE_T(cc, 1, Bc1);

    BALLOTS((cc+1)&1);
    asm volatile("s_waitcnt lgkmcnt(0)" ::: "memory");
  }
  { // peeled last chunk
    short8 Bc0[8], Bc1[8];
    const unsigned short* wb0 = lanebase + ((size_t)(jw32 + 30) << 12);
    #pragma unroll
    for (int c=0;c<8;++c) Bc0[c] = *(const short8*)(wb0 + (c<<9));
    #pragma unroll
    for (int c=0;c<8;++c) Bc1[c] = *(const short8*)(wb0 + 4096 + (c<<9));
    COMPUTE_T(15, 0, Bc0);
    COMPUTE_T(15, 1, Bc1);
  }
#undef COMPUTE_T
#undef MKAF
#undef BALLOTS

  // cross-wave combine, two passes (rowgroup 0 then 1); stride 132 for float4-aligned reads
  #pragma unroll 1
  for (int g = 0; g < 2; ++g){
    __syncthreads();
    #pragma unroll
    for (int c=0;c<8;++c){
      #pragma unroll
      for (int r=0;r<4;++r){
        const float v = g ? acc1[c][r] : acc0[c][r];
        smemc[(wave*16 + quad*4 + r)*132 + c*16 + m] = v;
      }
    }
    if (m == 0){
      #pragma unroll
      for (int r=0;r<4;++r) smemc[8448 + wave*16 + quad*4 + r] = g ? lf1[r] : lf0[r];
    }
    __syncthreads();

    const int rr = tid >> 5;
    const int c4 = (tid & 31) << 2;
    #pragma unroll
    for (int hh = 0; hh < 2; ++hh){
      const int row = rr + (hh<<3);
      const float l = smemc[8448+row] + smemc[8448+16+row]
                    + smemc[8448+32+row] + smemc[8448+48+row];
      const float rl = __builtin_amdgcn_rcpf(l);       // ~1 ulp, replaces 8 f32 divides
      float4 o4;
      #pragma unroll
      for (int k=0;k<4;++k){
        const int col = c4 + k;
        const float s = smemc[row*132+col] + smemc[(16+row)*132+col]
                      + smemc[(32+row)*132+col] + smemc[(48+row)*132+col];
        float v = s * rl;
        v = v > 0.f ? v : expm1f(v);                   // ELU (alpha=1)
        ((float*)&o4)[k] = v;
      }
      *(float4*)&out[((size_t)(b*GN + i0 + (g<<4) + row))*GF + c4] = o4;
    }
  }
}

extern "C" void kernel_launch(void* const* d_in, const int* in_sizes, int n_in,
                              void* d_out, int out_size, void* d_ws, size_t ws_size,
                              hipStream_t stream)
{
  (void)in_sizes; (void)n_in; (void)out_size; (void)ws_size;
  const float* h   = (const float*)d_in[0];
  const int*   adj = (const int*)d_in[1];
  const float* W   = (const float*)d_in[2];
  const float* a   = (const float*)d_in[3];
  float* out = (float*)d_out;

  char* ws = (char*)d_ws;
  unsigned short* whB   = (unsigned short*)ws;                    // 4 MB fragment-major
  float*          si    = (float*)(ws + (size_t)4*1024*1024);     // 64 KB
  unsigned short* EFh   = (unsigned short*)(ws + (size_t)4*1024*1024 + 64*1024);   // 64 KB

  gat_prep<<<GB*GN/16, 256, 0, stream>>>(h, W, a, whB, si, EFh);
  gat_main<<<GB*GN/32, 256, 0, stream>>>(adj, whB, si, EFh, out);
}

// Round 2
// 404.445 us; speedup vs baseline: 1.0137x; 1.0137x over previous
//
#include <hip/hip_runtime.h>

#define GN 4096
#define GF 128
#define GB 4

typedef __attribute__((ext_vector_type(8))) short short8;
typedef __attribute__((ext_vector_type(4))) float floatx4;

static __device__ __forceinline__ unsigned short f2bf(float x){
  unsigned int u = __float_as_uint(x);
  u += 0x7FFFu + ((u >> 16) & 1u);            // RNE
  return (unsigned short)(u >> 16);
}

// ---------- Kernel 1: Wh = h@W (f32), si, bf16 E/F tables, bf16 Wh fragment-major ----------
// whB layout: [b][jblk=j>>5][o][j&31] so a wave's B-fragment load is 1KB contiguous.
__global__ __launch_bounds__(256)
void gat_prep(const float* __restrict__ h, const float* __restrict__ W,
              const float* __restrict__ a, unsigned short* __restrict__ whB,
              float* __restrict__ si_g, unsigned short* __restrict__ EFh)
{
  __shared__ float hl[16*GF];                  // 8 KB
  __shared__ float red[2][2][16];
  const int tid = threadIdx.x;
  const int b   = blockIdx.x >> 8;
  const int r0  = (blockIdx.x & 255) << 4;
  const int o = tid & 127, g = tid >> 7;

  const float4* hb4 = (const float4*)(h + ((size_t)(b*GN + r0))*GF);
  ((float4*)hl)[tid]       = hb4[tid];
  ((float4*)hl)[tid + 256] = hb4[tid + 256];
  __syncthreads();

  float acc[8];
  #pragma unroll
  for (int r=0;r<8;++r) acc[r] = 0.f;
  const float* Wp = W + o;
  for (int f4=0; f4<32; ++f4){
    const float w0 = Wp[(f4*4+0)*GF];
    const float w1 = Wp[(f4*4+1)*GF];
    const float w2 = Wp[(f4*4+2)*GF];
    const float w3 = Wp[(f4*4+3)*GF];
    #pragma unroll
    for (int r=0;r<8;++r){
      const float4 h4 = *(const float4*)&hl[((g<<3)+r)*GF + (f4<<2)];
      acc[r] = fmaf(h4.x, w0, acc[r]);
      acc[r] = fmaf(h4.y, w1, acc[r]);
      acc[r] = fmaf(h4.z, w2, acc[r]);
      acc[r] = fmaf(h4.w, w3, acc[r]);
    }
  }

  const float ai = a[o], aj = a[GF + o];
  const int lane = tid & 63, wh = (tid >> 6) & 1;
  #pragma unroll
  for (int r=0;r<8;++r){
    float vi = acc[r]*ai, vj = acc[r]*aj;
    #pragma unroll
    for (int off=32; off; off>>=1){ vi += __shfl_down(vi, off); vj += __shfl_down(vj, off); }
    if (lane == 0){ red[0][wh][(g<<3)+r] = vi; red[1][wh][(g<<3)+r] = vj; }
  }

  // fragment-major bf16 store
  unsigned short us[8] __attribute__((aligned(16)));
  #pragma unroll
  for (int r=0;r<8;++r) us[r] = f2bf(acc[r]);
  {
    const int j0 = r0 + (g<<3);
    unsigned short* dst = whB + (((size_t)(b*128 + (j0>>5))*128 + o)<<5) + (j0&31);
    *(uint4*)dst = *(const uint4*)us;
  }

  __syncthreads();
  if (tid < 16){
    si_g[b*GN + r0 + tid] = red[0][0][tid] + red[0][1][tid];
  } else if (tid < 32){
    const int r = tid - 16;
    const float vsj = red[1][0][r] + red[1][1][r];
    EFh[(size_t)b*8192 + r0 + r]        = f2bf(__expf(vsj));
    EFh[(size_t)b*8192 + 4096 + r0 + r] = f2bf(__expf(0.2f*vsj));
  }
}

// ---------- Kernel 2: fused adj-stream + attention + PV, depth-2 per-wave pipeline ----------
// FIFO-aware schedule: per half-chunk [Bc(c)][adj(c+2)][COMPUTE(c): vmcnt(32)][BALLOT(c+1): no wait].
// The soonest-needed loads are always OLDEST in the vm queue, so per-wave outstanding
// never drops below 32 loads (8 KB) -> CU memory pipe continuously fed.
__global__ __launch_bounds__(256, 2)
void gat_main(const int* __restrict__ adj, const unsigned short* __restrict__ whB,
              const float* __restrict__ si_g, const unsigned short* __restrict__ EFh,
              float* __restrict__ out)
{
  __shared__ __align__(16) char smem[34304];
  unsigned short* sEj = (unsigned short*)smem;                       // [0,4096):E [4096,8192):F (bf16)
  unsigned long long* bits64 = (unsigned long long*)(smem + 16384);  // [4 waves][2 buf][32 rows]
  float* smemc = (float*)smem;                                       // combine (after K-loop)

  const int tid  = threadIdx.x;
  const int wave = tid >> 6, lane = tid & 63;
  const int b  = (blockIdx.x >> 1) & 3;                              // XCD-pair per batch
  const int i0 = ((((blockIdx.x >> 3) << 1) | (blockIdx.x & 1))) << 5;
  const int m = lane & 15, quad = lane >> 4, q8 = quad << 3;
  const int jw = wave << 10, jw32 = wave << 5;

  const int* adjb = adj + ((size_t)(b*GN + i0))*GN + jw + lane;

#define LOADVV(vv_, chunk_) do { \
    _Pragma("unroll") \
    for (int r=0;r<32;++r) vv_[r] = __builtin_nontemporal_load(adjb + ((chunk_)<<6) + (size_t)r*GN); \
  } while(0)

  // prologue: chunks 0,1 in flight before anything else
  int vvA[32], vvB[32];
  LOADVV(vvA, 0);
  LOADVV(vvB, 1);

  const float si0 = si_g[(size_t)b*GN + i0 + m];
  const float si1 = si_g[(size_t)b*GN + i0 + 16 + m];
  const float Ri0 = __expf(-0.8f*si0), Ri1 = __expf(-0.8f*si1);
  const unsigned short* lanebase = whB + ((size_t)b<<19) + (m<<5) + q8;

  // --- EF staging (16KB) ---
  {
    const uint4* Eg = (const uint4*)(EFh + (size_t)b*8192);
    uint4* sE4 = (uint4*)sEj;
    #pragma unroll
    for (int k=0;k<4;++k) sE4[tid + (k<<8)] = Eg[tid + (k<<8)];
  }

  floatx4 acc0[8], acc1[8];
  #pragma unroll
  for (int c=0;c<8;++c){ acc0[c] = (floatx4){0.f,0.f,0.f,0.f}; acc1[c] = (floatx4){0.f,0.f,0.f,0.f}; }
  floatx4 lf0 = (floatx4){0.f,0.f,0.f,0.f}, lf1 = (floatx4){0.f,0.f,0.f,0.f};
  const short8 ones8 = {0x3F80,0x3F80,0x3F80,0x3F80,0x3F80,0x3F80,0x3F80,0x3F80};

#define BALLOTS(vv_, bufp_) do { \
    unsigned long long* bw = bits64 + (((wave<<1) | (bufp_)) << 5); \
    _Pragma("unroll") \
    for (int r=0;r<32;++r){ \
      const unsigned long long mm = __ballot(vv_[r] > 0); \
      if (lane == 0) bw[r] = mm; \
    } \
    asm volatile("s_waitcnt lgkmcnt(0)" ::: "memory"); \
  } while(0)

#define BCLOAD(Bc_, chunk_) do { \
    const unsigned short* wb = lanebase + ((size_t)(jw32 + ((chunk_)<<1)) << 12); \
    _Pragma("unroll") \
    for (int c=0;c<8;++c) Bc_[c]   = *(const short8*)(wb + (c<<9)); \
    _Pragma("unroll") \
    for (int c=0;c<8;++c) Bc_[8+c] = *(const short8*)(wb + 4096 + (c<<9)); \
  } while(0)

// per 64-j chunk: 2 steps of 32 j. Shared E/F unpack across row-groups; bf16 pack via
// v_cvt_pk_bf16_f32; adjacency mask applied on the packed word (masked half -> 0.0).
#define COMPUTE(chunk_, bufp_, Bc_) do { \
    const unsigned int* bwp = (const unsigned int*)(bits64 + (((wave<<1) | (bufp_)) << 5)); \
    _Pragma("unroll") \
    for (int t=0;t<2;++t){ \
      const unsigned int sh0 = bwp[(m<<1)|t] >> q8; \
      const unsigned int sh1 = bwp[((m+16)<<1)|t] >> q8; \
      const int jj = jw + ((((chunk_)<<1)|t)<<5) + q8; \
      const short8 Es = *(const short8*)&sEj[jj]; \
      const short8 Fs = *(const short8*)&sEj[4096 + jj]; \
      const unsigned int* Eu = (const unsigned int*)&Es; \
      const unsigned int* Fu = (const unsigned int*)&Fs; \
      unsigned int aw0[4], aw1[4]; \
      _Pragma("unroll") \
      for (int p=0;p<4;++p){ \
        const float E0 = __uint_as_float(Eu[p] << 16); \
        const float E1 = __uint_as_float(Eu[p] & 0xFFFF0000u); \
        const float F0 = __uint_as_float(Fu[p] << 16); \
        const float F1 = __uint_as_float(Fu[p] & 0xFFFF0000u); \
        const float p00 = fmaxf(E0, Ri0*F0), p01 = fmaxf(E1, Ri0*F1); \
        const float p10 = fmaxf(E0, Ri1*F0), p11 = fmaxf(E1, Ri1*F1); \
        unsigned int w0, w1; \
        asm("v_cvt_pk_bf16_f32 %0, %1, %2" : "=v"(w0) : "v"(p00), "v"(p01)); \
        asm("v_cvt_pk_bf16_f32 %0, %1, %2" : "=v"(w1) : "v"(p10), "v"(p11)); \
        const unsigned int k00 = (unsigned int)(((int)(sh0 << (31-2*p))) >> 31); \
        const unsigned int k01 = (unsigned int)(((int)(sh0 << (30-2*p))) >> 31); \
        const unsigned int k10 = (unsigned int)(((int)(sh1 << (31-2*p))) >> 31); \
        const unsigned int k11 = (unsigned int)(((int)(sh1 << (30-2*p))) >> 31); \
        aw0[p] = w0 & ((k00 & 0xFFFFu) | (k01 << 16)); \
        aw1[p] = w1 & ((k10 & 0xFFFFu) | (k11 << 16)); \
      } \
      const short8 af0 = *(const short8*)aw0; \
      const short8 af1 = *(const short8*)aw1; \
      _Pragma("unroll") \
      for (int c=0;c<8;++c){ \
        acc0[c] = __builtin_amdgcn_mfma_f32_16x16x32_bf16(af0, Bc_[(t<<3)+c], acc0[c], 0, 0, 0); \
        acc1[c] = __builtin_amdgcn_mfma_f32_16x16x32_bf16(af1, Bc_[(t<<3)+c], acc1[c], 0, 0, 0); \
      } \
      lf0 = __builtin_amdgcn_mfma_f32_16x16x32_bf16(af0, ones8, lf0, 0, 0, 0); \
      lf1 = __builtin_amdgcn_mfma_f32_16x16x32_bf16(af1, ones8, lf1, 0, 0, 0); \
    } \
  } while(0)

  __syncthreads();                 // sEj staged (drains prologue adj loads too; one-time cost)

  BALLOTS(vvA, 0);                 // bits(0) -> buf0; vvB still in flight

  #pragma unroll 1
  for (int ci = 0; ci < 7; ++ci){
    const int c0 = ci << 1;
    // EVEN half: compute c0 (buf0), prefetch c0+2 -> vvA, ballot c0+1 -> buf1
    {
      short8 BcA[16];
      BCLOAD(BcA, c0);             // issued first: oldest among this half's loads
      LOADVV(vvA, c0+2);           // newest: survives COMPUTE's vmcnt(32) wait
      COMPUTE(c0, 0, BcA);
      BALLOTS(vvB, 1);             // vvB older than BcA -> already retired, zero stall
    }
    // ODD half: compute c0+1 (buf1), prefetch c0+3 -> vvB, ballot c0+2 -> buf0
    {
      short8 BcB[16];
      BCLOAD(BcB, c0+1);
      LOADVV(vvB, c0+3);
      COMPUTE(c0+1, 1, BcB);
      BALLOTS(vvA, 0);
    }
  }
  { short8 BcA[16]; BCLOAD(BcA, 14); COMPUTE(14, 0, BcA); }
  BALLOTS(vvB, 1);
  { short8 BcB[16]; BCLOAD(BcB, 15); COMPUTE(15, 1, BcB); }

#undef COMPUTE
#undef BCLOAD
#undef BALLOTS
#undef LOADVV

  // cross-wave combine, two passes (rowgroup 0 then 1); stride 132 for float4-aligned reads
  #pragma unroll 1
  for (int g = 0; g < 2; ++g){
    __syncthreads();
    #pragma unroll
    for (int c=0;c<8;++c){
      #pragma unroll
      for (int r=0;r<4;++r){
        const float v = g ? acc1[c][r] : acc0[c][r];
        smemc[(wave*16 + quad*4 + r)*132 + c*16 + m] = v;
      }
    }
    if (m == 0){
      #pragma unroll
      for (int r=0;r<4;++r) smemc[8448 + wave*16 + quad*4 + r] = g ? lf1[r] : lf0[r];
    }
    __syncthreads();

    const int rr = tid >> 5;
    const int c4 = (tid & 31) << 2;
    #pragma unroll
    for (int hh = 0; hh < 2; ++hh){
      const int row = rr + (hh<<3);
      const float l = smemc[8448+row] + smemc[8448+16+row]
                    + smemc[8448+32+row] + smemc[8448+48+row];
      const float rl = __builtin_amdgcn_rcpf(l);       // ~1 ulp, replaces 8 f32 divides
      float4 o4;
      #pragma unroll
      for (int k=0;k<4;++k){
        const int col = c4 + k;
        const float s = smemc[row*132+col] + smemc[(16+row)*132+col]
                      + smemc[(32+row)*132+col] + smemc[(48+row)*132+col];
        float v = s * rl;
        v = v > 0.f ? v : expm1f(v);                   // ELU (alpha=1)
        ((float*)&o4)[k] = v;
      }
      *(float4*)&out[((size_t)(b*GN + i0 + (g<<4) + row))*GF + c4] = o4;
    }
  }
}

extern "C" void kernel_launch(void* const* d_in, const int* in_sizes, int n_in,
                              void* d_out, int out_size, void* d_ws, size_t ws_size,
                              hipStream_t stream)
{
  (void)in_sizes; (void)n_in; (void)out_size; (void)ws_size;
  const float* h   = (const float*)d_in[0];
  const int*   adj = (const int*)d_in[1];
  const float* W   = (const float*)d_in[2];
  const float* a   = (const float*)d_in[3];
  float* out = (float*)d_out;

  char* ws = (char*)d_ws;
  unsigned short* whB   = (unsigned short*)ws;                    // 4 MB fragment-major
  float*          si    = (float*)(ws + (size_t)4*1024*1024);     // 64 KB
  unsigned short* EFh   = (unsigned short*)(ws + (size_t)4*1024*1024 + 64*1024);   // 64 KB

  gat_prep<<<GB*GN/16, 256, 0, stream>>>(h, W, a, whB, si, EFh);
  gat_main<<<GB*GN/32, 256, 0, stream>>>(adj, whB, si, EFh, out);
}

// Round 3
// 397.157 us; speedup vs baseline: 1.0323x; 1.0184x over previous
//
#include <hip/hip_runtime.h>

#define GN 4096
#define GF 128
#define GB 4

typedef __attribute__((ext_vector_type(8))) short short8;
typedef __attribute__((ext_vector_type(4))) float floatx4;
typedef __attribute__((ext_vector_type(2))) int intx2;

static __device__ __forceinline__ unsigned short f2bf(float x){
  unsigned int u = __float_as_uint(x);
  u += 0x7FFFu + ((u >> 16) & 1u);            // RNE
  return (unsigned short)(u >> 16);
}

// J-permutation (parity within each 128-j window) so gat_main can read adj as dwordx2:
// lane l component k <-> j = 2l + k; table index J = (j&~127) + 64*(j&1) + ((j&127)>>1).
// whB / E / F are all written in J-order; bits, fragments, tables then agree untouched.

// ---------- Kernel 1: Wh = h@W (f32), si, bf16 E/F tables, bf16 Wh fragment-major ----------
__global__ __launch_bounds__(256)
void gat_prep(const float* __restrict__ h, const float* __restrict__ W,
              const float* __restrict__ a, unsigned short* __restrict__ whB,
              float* __restrict__ si_g, unsigned short* __restrict__ EFh)
{
  __shared__ float hl[16*GF];                  // 8 KB
  __shared__ float red[2][2][16];
  const int tid = threadIdx.x;
  const int b   = blockIdx.x >> 8;
  const int r0  = (blockIdx.x & 255) << 4;
  const int o = tid & 127, g = tid >> 7;

  const float4* hb4 = (const float4*)(h + ((size_t)(b*GN + r0))*GF);
  ((float4*)hl)[tid]       = hb4[tid];
  ((float4*)hl)[tid + 256] = hb4[tid + 256];
  __syncthreads();

  float acc[8];
  #pragma unroll
  for (int r=0;r<8;++r) acc[r] = 0.f;
  const float* Wp = W + o;
  for (int f4=0; f4<32; ++f4){
    const float w0 = Wp[(f4*4+0)*GF];
    const float w1 = Wp[(f4*4+1)*GF];
    const float w2 = Wp[(f4*4+2)*GF];
    const float w3 = Wp[(f4*4+3)*GF];
    #pragma unroll
    for (int r=0;r<8;++r){
      const float4 h4 = *(const float4*)&hl[((g<<3)+r)*GF + (f4<<2)];
      acc[r] = fmaf(h4.x, w0, acc[r]);
      acc[r] = fmaf(h4.y, w1, acc[r]);
      acc[r] = fmaf(h4.z, w2, acc[r]);
      acc[r] = fmaf(h4.w, w3, acc[r]);
    }
  }

  const float ai = a[o], aj = a[GF + o];
  const int lane = tid & 63, wh = (tid >> 6) & 1;
  #pragma unroll
  for (int r=0;r<8;++r){
    float vi = acc[r]*ai, vj = acc[r]*aj;
    #pragma unroll
    for (int off=32; off; off>>=1){ vi += __shfl_down(vi, off); vj += __shfl_down(vj, off); }
    if (lane == 0){ red[0][wh][(g<<3)+r] = vi; red[1][wh][(g<<3)+r] = vj; }
  }

  // fragment-major bf16 store in J-order: evens -> Je.., odds -> Je+64..
  unsigned short us[8] __attribute__((aligned(16)));
  #pragma unroll
  for (int r=0;r<8;++r) us[r] = f2bf(acc[r]);
  {
    const int j0 = r0 + (g<<3);
    const int Je = (j0 & ~127) + ((j0 & 127) >> 1);
    unsigned short ev[4] __attribute__((aligned(8))) = {us[0],us[2],us[4],us[6]};
    unsigned short od[4] __attribute__((aligned(8))) = {us[1],us[3],us[5],us[7]};
    unsigned short* d0 = whB + (((size_t)(b*128 + (Je>>5))*128 + o)<<5) + (Je&31);
    *(uint2*)d0          = *(const uint2*)ev;
    *(uint2*)(d0 + 8192) = *(const uint2*)od;   // J+64 -> jblk+2
  }

  __syncthreads();
  if (tid < 16){
    si_g[b*GN + r0 + tid] = red[0][0][tid] + red[0][1][tid];
  } else if (tid < 32){
    const int r = tid - 16;
    const int jj = r0 + r;
    const int J  = (jj & ~127) + ((jj & 1) << 6) + ((jj & 127) >> 1);
    const float vsj = red[1][0][r] + red[1][1][r];
    EFh[(size_t)b*8192 + J]        = f2bf(__expf(vsj));
    EFh[(size_t)b*8192 + 4096 + J] = f2bf(__expf(0.2f*vsj));
  }
}

// ---------- Kernel 2: fused adj-stream + attention + PV ----------
// adj read as dwordx2 (512B contiguous per row-visit, halving request count) over
// 128-j superchunks; per-wave row rotation spreads concurrent DRAM row streams.
__global__ __launch_bounds__(256, 2)
void gat_main(const int* __restrict__ adj, const unsigned short* __restrict__ whB,
              const float* __restrict__ si_g, const unsigned short* __restrict__ EFh,
              float* __restrict__ out)
{
  __shared__ __align__(16) char smem[34304];
  unsigned short* sEj = (unsigned short*)smem;                       // [0,4096):E [4096,8192):F (bf16, J-order)
  unsigned long long* bits64 = (unsigned long long*)(smem + 16384);  // [4 waves][2 buf][32 rows][2 k]
  float* smemc = (float*)smem;                                       // combine (after K-loop)

  const int tid  = threadIdx.x;
  const int wave = tid >> 6, lane = tid & 63;
  const int b  = (blockIdx.x >> 1) & 3;                              // XCD-pair per batch
  const int i0 = ((((blockIdx.x >> 3) << 1) | (blockIdx.x & 1))) << 5;
  const int m = lane & 15, quad = lane >> 4, q8 = quad << 3;
  const int jw = wave << 10, jw32 = wave << 5;
  const int rrot = wave << 3;

  const intx2* adjb2 = (const intx2*)(adj + ((size_t)(b*GN + i0))*GN + jw) + lane;

#define LOADVV(vv_, sc_) do { \
    _Pragma("unroll") \
    for (int r=0;r<32;++r){ \
      const int rr = (r + rrot) & 31; \
      vv_[r] = __builtin_nontemporal_load(adjb2 + ((sc_)<<6) + rr*(GN/2)); \
    } \
  } while(0)

  // prologue: superchunk 0 (128 j) in flight before anything else
  intx2 vv[32];
  LOADVV(vv, 0);

  const float si0 = si_g[(size_t)b*GN + i0 + m];
  const float si1 = si_g[(size_t)b*GN + i0 + 16 + m];
  const float Ri0 = __expf(-0.8f*si0), Ri1 = __expf(-0.8f*si1);
  const unsigned short* lanebase = whB + ((size_t)b<<19) + (m<<5) + q8;

  // --- EF staging (16KB, already J-ordered) ---
  {
    const uint4* Eg = (const uint4*)(EFh + (size_t)b*8192);
    uint4* sE4 = (uint4*)sEj;
    #pragma unroll
    for (int k=0;k<4;++k) sE4[tid + (k<<8)] = Eg[tid + (k<<8)];
  }

  floatx4 acc0[8], acc1[8];
  #pragma unroll
  for (int c=0;c<8;++c){ acc0[c] = (floatx4){0.f,0.f,0.f,0.f}; acc1[c] = (floatx4){0.f,0.f,0.f,0.f}; }
  floatx4 lf0 = (floatx4){0.f,0.f,0.f,0.f}, lf1 = (floatx4){0.f,0.f,0.f,0.f};
  const short8 ones8 = {0x3F80,0x3F80,0x3F80,0x3F80,0x3F80,0x3F80,0x3F80,0x3F80};

// ballot-pack superchunk: 2 words per row (k=0: even-j lanes, k=1: odd-j lanes)
#define BALLOTS(vv_, scdst_) do { \
    unsigned long long* bw = bits64 + (((wave<<1) | ((scdst_)&1)) << 6); \
    _Pragma("unroll") \
    for (int r=0;r<32;++r){ \
      const int rr = (r + rrot) & 31; \
      const unsigned long long m0 = __ballot(vv_[r].x > 0); \
      const unsigned long long m1 = __ballot(vv_[r].y > 0); \
      if (lane == 0){ bw[(rr<<1)] = m0; bw[(rr<<1)|1] = m1; } \
    } \
    asm volatile("s_waitcnt lgkmcnt(0)" ::: "memory"); \
  } while(0)

#define BCLOAD(Bc_, chunk_) do { \
    const unsigned short* wb = lanebase + ((size_t)(jw32 + ((chunk_)<<1)) << 12); \
    _Pragma("unroll") \
    for (int c=0;c<8;++c) Bc_[c]   = *(const short8*)(wb + (c<<9)); \
    _Pragma("unroll") \
    for (int c=0;c<8;++c) Bc_[8+c] = *(const short8*)(wb + 4096 + (c<<9)); \
  } while(0)

// one 64-J chunk (= parity class k of superchunk sc): 2 t-steps of 32 J
#define COMPUTE_CH(sc_, k_, Bc_) do { \
    const unsigned int* bwp = (const unsigned int*)(bits64 + (((wave<<1) | ((sc_)&1)) << 6)); \
    _Pragma("unroll") \
    for (int t=0;t<2;++t){ \
      const unsigned int sh0 = bwp[(m<<2)|((k_)<<1)|t] >> q8; \
      const unsigned int sh1 = bwp[((m+16)<<2)|((k_)<<1)|t] >> q8; \
      const int jj = jw + ((sc_)<<7) + ((k_)<<6) + (t<<5) + q8; \
      const short8 Es = *(const short8*)&sEj[jj]; \
      const short8 Fs = *(const short8*)&sEj[4096 + jj]; \
      const unsigned int* Eu = (const unsigned int*)&Es; \
      const unsigned int* Fu = (const unsigned int*)&Fs; \
      unsigned int aw0[4], aw1[4]; \
      _Pragma("unroll") \
      for (int p=0;p<4;++p){ \
        const float E0 = __uint_as_float(Eu[p] << 16); \
        const float E1 = __uint_as_float(Eu[p] & 0xFFFF0000u); \
        const float F0 = __uint_as_float(Fu[p] << 16); \
        const float F1 = __uint_as_float(Fu[p] & 0xFFFF0000u); \
        const float p00 = fmaxf(E0, Ri0*F0), p01 = fmaxf(E1, Ri0*F1); \
        const float p10 = fmaxf(E0, Ri1*F0), p11 = fmaxf(E1, Ri1*F1); \
        unsigned int w0, w1; \
        asm("v_cvt_pk_bf16_f32 %0, %1, %2" : "=v"(w0) : "v"(p00), "v"(p01)); \
        asm("v_cvt_pk_bf16_f32 %0, %1, %2" : "=v"(w1) : "v"(p10), "v"(p11)); \
        const unsigned int k00 = (unsigned int)(((int)(sh0 << (31-2*p))) >> 31); \
        const unsigned int k01 = (unsigned int)(((int)(sh0 << (30-2*p))) >> 31); \
        const unsigned int k10 = (unsigned int)(((int)(sh1 << (31-2*p))) >> 31); \
        const unsigned int k11 = (unsigned int)(((int)(sh1 << (30-2*p))) >> 31); \
        aw0[p] = w0 & ((k00 & 0xFFFFu) | (k01 << 16)); \
        aw1[p] = w1 & ((k10 & 0xFFFFu) | (k11 << 16)); \
      } \
      const short8 af0 = *(const short8*)aw0; \
      const short8 af1 = *(const short8*)aw1; \
      _Pragma("unroll") \
      for (int c=0;c<8;++c){ \
        acc0[c] = __builtin_amdgcn_mfma_f32_16x16x32_bf16(af0, Bc_[(t<<3)+c], acc0[c], 0, 0, 0); \
        acc1[c] = __builtin_amdgcn_mfma_f32_16x16x32_bf16(af1, Bc_[(t<<3)+c], acc1[c], 0, 0, 0); \
      } \
      lf0 = __builtin_amdgcn_mfma_f32_16x16x32_bf16(af0, ones8, lf0, 0, 0, 0); \
      lf1 = __builtin_amdgcn_mfma_f32_16x16x32_bf16(af1, ones8, lf1, 0, 0, 0); \
    } \
  } while(0)

  __syncthreads();                 // sEj staged (drains prologue loads; one-time cost)

  BALLOTS(vv, 0);                  // superchunk 0 -> buf0

  #pragma unroll 1
  for (int sc = 0; sc < 7; ++sc){
    {
      short8 Bc[16];
      BCLOAD(Bc, (sc<<1));         // 16 L2 loads, oldest this superchunk
      LOADVV(vv, sc+1);            // 32 HBM dwordx2, stay in flight through compute
      COMPUTE_CH(sc, 0, Bc);       // waits vmcnt(32): vv kept outstanding
    }
    {
      short8 Bc[16];
      BCLOAD(Bc, (sc<<1)|1);
      COMPUTE_CH(sc, 1, Bc);       // drains vv too (issued ~2 t-steps earlier)
    }
    BALLOTS(vv, sc+1);             // vv complete: near-zero stall
  }
  { short8 Bc[16]; BCLOAD(Bc, 14); COMPUTE_CH(7, 0, Bc); }
  { short8 Bc[16]; BCLOAD(Bc, 15); COMPUTE_CH(7, 1, Bc); }

#undef COMPUTE_CH
#undef BCLOAD
#undef BALLOTS
#undef LOADVV

  // cross-wave combine, two passes (rowgroup 0 then 1); stride 132 for float4-aligned reads
  #pragma unroll 1
  for (int g = 0; g < 2; ++g){
    __syncthreads();
    #pragma unroll
    for (int c=0;c<8;++c){
      #pragma unroll
      for (int r=0;r<4;++r){
        const float v = g ? acc1[c][r] : acc0[c][r];
        smemc[(wave*16 + quad*4 + r)*132 + c*16 + m] = v;
      }
    }
    if (m == 0){
      #pragma unroll
      for (int r=0;r<4;++r) smemc[8448 + wave*16 + quad*4 + r] = g ? lf1[r] : lf0[r];
    }
    __syncthreads();

    const int rr = tid >> 5;
    const int c4 = (tid & 31) << 2;
    #pragma unroll
    for (int hh = 0; hh < 2; ++hh){
      const int row = rr + (hh<<3);
      const float l = smemc[8448+row] + smemc[8448+16+row]
                    + smemc[8448+32+row] + smemc[8448+48+row];
      const float rl = __builtin_amdgcn_rcpf(l);       // ~1 ulp, replaces 8 f32 divides
      float4 o4;
      #pragma unroll
      for (int k=0;k<4;++k){
        const int col = c4 + k;
        const float s = smemc[row*132+col] + smemc[(16+row)*132+col]
                      + smemc[(32+row)*132+col] + smemc[(48+row)*132+col];
        float v = s * rl;
        v = v > 0.f ? v : expm1f(v);                   // ELU (alpha=1)
        ((float*)&o4)[k] = v;
      }
      *(float4*)&out[((size_t)(b*GN + i0 + (g<<4) + row))*GF + c4] = o4;
    }
  }
}

extern "C" void kernel_launch(void* const* d_in, const int* in_sizes, int n_in,
                              void* d_out, int out_size, void* d_ws, size_t ws_size,
                              hipStream_t stream)
{
  (void)in_sizes; (void)n_in; (void)out_size; (void)ws_size;
  const float* h   = (const float*)d_in[0];
  const int*   adj = (const int*)d_in[1];
  const float* W   = (const float*)d_in[2];
  const float* a   = (const float*)d_in[3];
  float* out = (float*)d_out;

  char* ws = (char*)d_ws;
  unsigned short* whB   = (unsigned short*)ws;                    // 4 MB fragment-major (J-order)
  float*          si    = (float*)(ws + (size_t)4*1024*1024);     // 64 KB
  unsigned short* EFh   = (unsigned short*)(ws + (size_t)4*1024*1024 + 64*1024);   // 64 KB

  gat_prep<<<GB*GN/16, 256, 0, stream>>>(h, W, a, whB, si, EFh);
  gat_main<<<GB*GN/32, 256, 0, stream>>>(adj, whB, si, EFh, out);
}